// Round 2
// 688.914 us; speedup vs baseline: 1.0121x; 1.0121x over previous
//
#include <hip/hip_runtime.h>

typedef _Float16 h16;
typedef _Float16 h16x8 __attribute__((ext_vector_type(8)));
typedef float    f32x4 __attribute__((ext_vector_type(4)));

static constexpr int NN  = 32768;
static constexpr int EE  = 262144;
static constexpr int TT  = 262144;
static constexpr int D   = 128;   // DN = DE
static constexpr int K3  = 640;   // 3*DN + 2*DE
static constexpr int LDA = 72;    // padded LDS row stride (64 + 8) in h16
#define EPS 1e-5f

// ---------------------------------------------------------------------------
// fp32 -> fp16 converter, 8 elems/thread
// ---------------------------------------------------------------------------
__global__ __launch_bounds__(256) void cvt_f32_f16(
    const float* __restrict__ src, h16* __restrict__ dst, int n8)
{
    const int i = blockIdx.x * 256 + threadIdx.x;
    if (i >= n8) return;
    const float4* s = reinterpret_cast<const float4*>(src);
    const float4 a = s[2 * i], b = s[2 * i + 1];
    h16x8 o;
    o[0] = (h16)a.x; o[1] = (h16)a.y; o[2] = (h16)a.z; o[3] = (h16)a.w;
    o[4] = (h16)b.x; o[5] = (h16)b.y; o[6] = (h16)b.z; o[7] = (h16)b.w;
    *reinterpret_cast<h16x8*>(dst + 8 * i) = o;
}

// ---------------------------------------------------------------------------
// c3: gathered A [T,640](fp16) @ W3^T [640,256](fp16) + b3 -> LN(256) ->
// sigmoid*tanh -> atomicAdd scatter into acc3[E,128] (fp32, = d_out)
// Block 256 thr = 4 waves, M-tile 128 (32 rows/wave), K chunks of 64.
// One-deep software pipeline: chunk c+1's gathers issue before MFMA(c).
// ---------------------------------------------------------------------------
__global__ __launch_bounds__(256, 2) void c3_kernel(
    const h16*  __restrict__ nodeh, const float* __restrict__ edge,
    const h16*  __restrict__ edgeh,
    const int* __restrict__ idx_i, const int* __restrict__ idx_j,
    const int* __restrict__ idx_k, const int* __restrict__ idx_ji,
    const int* __restrict__ idx_kj,
    const h16* __restrict__ W3h, const float* __restrict__ b3,
    const float* __restrict__ g3, const float* __restrict__ be3,
    float* __restrict__ acc3)
{
    __shared__ h16 As[128 * LDA];   // 18 KB
    __shared__ h16 Bs[256 * LDA];   // 36 KB

    const int tid  = threadIdx.x;
    const int lane = tid & 63;
    const int wave = tid >> 6;
    const int l15  = lane & 15;
    const int quad = lane >> 4;
    const int m0   = blockIdx.x * 128;

    f32x4 acc[2][16];
    #pragma unroll
    for (int mt = 0; mt < 2; ++mt)
        #pragma unroll
        for (int nt = 0; nt < 16; ++nt)
            acc[mt][nt] = (f32x4){0.f, 0.f, 0.f, 0.f};

    const int r = tid >> 1;   // A staging: 2 threads per row
    const int h = tid & 1;    // which 32-elem half of the 64-col chunk

    // hoisted gather rows for this thread's staging row
    const size_t rI  = (size_t)idx_i [m0 + r];
    const size_t rJ  = (size_t)idx_j [m0 + r];
    const size_t rK  = (size_t)idx_k [m0 + r];
    const size_t rJI = (size_t)idx_ji[m0 + r];
    const size_t rKJ = (size_t)idx_kj[m0 + r];

    h16x8 av[4], bv[8];

#define LDC3(c)                                                                          \
    {                                                                                    \
        const int seg  = (c) >> 1;                                                       \
        const int half = (c) & 1;                                                        \
        const size_t row = (seg == 0) ? rI : (seg == 1) ? rJ                             \
                         : (seg == 2) ? rK : (seg == 3) ? rJI : rKJ;                     \
        if (seg < 3) {                                                                   \
            const h16x8* sp = reinterpret_cast<const h16x8*>(                            \
                nodeh + row * D + half * 64 + h * 32);                                   \
            _Pragma("unroll")                                                            \
            for (int q = 0; q < 4; ++q) av[q] = sp[q];                                   \
        } else if (edgeh) {                                                              \
            const h16x8* sp = reinterpret_cast<const h16x8*>(                            \
                edgeh + row * D + half * 64 + h * 32);                                   \
            _Pragma("unroll")                                                            \
            for (int q = 0; q < 4; ++q) av[q] = sp[q];                                   \
        } else {                                                                         \
            const float4* fp = reinterpret_cast<const float4*>(                          \
                edge + row * D + half * 64 + h * 32);                                    \
            _Pragma("unroll")                                                            \
            for (int q = 0; q < 4; ++q) {                                                \
                const float4 u = fp[2 * q], vv = fp[2 * q + 1];                          \
                h16x8 t;                                                                 \
                t[0] = (h16)u.x;  t[1] = (h16)u.y;  t[2] = (h16)u.z;  t[3] = (h16)u.w;   \
                t[4] = (h16)vv.x; t[5] = (h16)vv.y; t[6] = (h16)vv.z; t[7] = (h16)vv.w;  \
                av[q] = t;                                                               \
            }                                                                            \
        }                                                                                \
        const h16x8* wp = reinterpret_cast<const h16x8*>(                                \
            W3h + (size_t)tid * K3 + (c) * 64);                                          \
        _Pragma("unroll")                                                                \
        for (int q = 0; q < 8; ++q) bv[q] = wp[q];                                       \
    }

    LDC3(0);   // prologue prefetch

    #pragma unroll 1
    for (int c = 0; c < 10; ++c) {
        __syncthreads();   // previous chunk's fragment reads complete
        h16x8* ad = reinterpret_cast<h16x8*>(&As[r * LDA + h * 32]);
        #pragma unroll
        for (int q = 0; q < 4; ++q) ad[q] = av[q];
        h16x8* bd = reinterpret_cast<h16x8*>(&Bs[tid * LDA]);
        #pragma unroll
        for (int q = 0; q < 8; ++q) bd[q] = bv[q];
        __syncthreads();

        if (c < 9) LDC3(c + 1);   // issue next chunk's gathers under MFMA

        #pragma unroll
        for (int kk = 0; kk < 64; kk += 32) {
            h16x8 a0 = *reinterpret_cast<const h16x8*>(&As[(wave*32      + l15) * LDA + kk + quad*8]);
            h16x8 a1 = *reinterpret_cast<const h16x8*>(&As[(wave*32 + 16 + l15) * LDA + kk + quad*8]);
            #pragma unroll
            for (int nt = 0; nt < 16; ++nt) {
                h16x8 b = *reinterpret_cast<const h16x8*>(&Bs[(nt*16 + l15) * LDA + kk + quad*8]);
                acc[0][nt] = __builtin_amdgcn_mfma_f32_16x16x32_f16(a0, b, acc[0][nt], 0, 0, 0);
                acc[1][nt] = __builtin_amdgcn_mfma_f32_16x16x32_f16(a1, b, acc[1][nt], 0, 0, 0);
            }
        }
    }
#undef LDC3

    // ---- epilogue: +b3, LN(256), gate, atomic scatter ----
    float bias[16], gg[16], bb[16];
    #pragma unroll
    for (int nt = 0; nt < 16; ++nt) {
        const int cc = nt * 16 + l15;
        bias[nt] = b3[cc]; gg[nt] = g3[cc]; bb[nt] = be3[cc];
    }
    #pragma unroll
    for (int mt = 0; mt < 2; ++mt) {
        #pragma unroll
        for (int rg = 0; rg < 4; ++rg) {
            float v[16];
            float s = 0.f, s2 = 0.f;
            #pragma unroll
            for (int nt = 0; nt < 16; ++nt) {
                v[nt] = acc[mt][nt][rg] + bias[nt];
                s += v[nt]; s2 += v[nt] * v[nt];
            }
            #pragma unroll
            for (int m = 1; m < 16; m <<= 1) {   // reduce within the 16-lane quad
                s  += __shfl_xor(s,  m, 64);
                s2 += __shfl_xor(s2, m, 64);
            }
            const float mean = s * (1.f / 256.f);
            const float var  = s2 * (1.f / 256.f) - mean * mean;
            const float inv  = rsqrtf(var + EPS);
            const int rowg   = m0 + wave * 32 + mt * 16 + quad * 4 + rg;
            const size_t e   = (size_t)idx_ji[rowg];
            #pragma unroll
            for (int nt = 0; nt < 8; ++nt) {
                const float f   = (v[nt]     - mean) * inv * gg[nt]     + bb[nt];
                const float co  = (v[nt + 8] - mean) * inv * gg[nt + 8] + bb[nt + 8];
                const float msg = (1.f / (1.f + __expf(-f))) * tanhf(co);
                atomicAdd(&acc3[e * D + nt * 16 + l15], msg);
            }
        }
    }
}

// ---------------------------------------------------------------------------
// c2: (node[i]*node[j]) [E,128] @ W2^T [128,256] + b2 -> LN(256) -> gate ->
// LN(128) -> store fp16 c2_emb into ws. Same one-deep pipeline.
// ---------------------------------------------------------------------------
__global__ __launch_bounds__(256, 2) void c2_kernel(
    const h16* __restrict__ nodeh,
    const int* __restrict__ ei, const int* __restrict__ ej,
    const h16* __restrict__ W2h, const float* __restrict__ b2,
    const float* __restrict__ g2, const float* __restrict__ be2,
    const float* __restrict__ g22, const float* __restrict__ be22,
    h16* __restrict__ c2emb)
{
    __shared__ h16 As[128 * LDA];
    __shared__ h16 Bs[256 * LDA];

    const int tid  = threadIdx.x;
    const int lane = tid & 63;
    const int wave = tid >> 6;
    const int l15  = lane & 15;
    const int quad = lane >> 4;
    const int m0   = blockIdx.x * 128;

    f32x4 acc[2][16];
    #pragma unroll
    for (int mt = 0; mt < 2; ++mt)
        #pragma unroll
        for (int nt = 0; nt < 16; ++nt)
            acc[mt][nt] = (f32x4){0.f, 0.f, 0.f, 0.f};

    const int r = tid >> 1;
    const int h = tid & 1;
    const size_t ri = (size_t)ei[m0 + r];
    const size_t rj = (size_t)ej[m0 + r];

    h16x8 av[4], bv[8];

#define LDC2(c)                                                                          \
    {                                                                                    \
        const h16x8* si = reinterpret_cast<const h16x8*>(                                \
            nodeh + ri * D + (c) * 64 + h * 32);                                         \
        const h16x8* sj = reinterpret_cast<const h16x8*>(                                \
            nodeh + rj * D + (c) * 64 + h * 32);                                         \
        _Pragma("unroll")                                                                \
        for (int q = 0; q < 4; ++q) av[q] = si[q] * sj[q];                               \
        const h16x8* wp = reinterpret_cast<const h16x8*>(                                \
            W2h + (size_t)tid * D + (c) * 64);                                           \
        _Pragma("unroll")                                                                \
        for (int q = 0; q < 8; ++q) bv[q] = wp[q];                                       \
    }

    LDC2(0);

    #pragma unroll 1
    for (int c = 0; c < 2; ++c) {
        __syncthreads();
        h16x8* ad = reinterpret_cast<h16x8*>(&As[r * LDA + h * 32]);
        #pragma unroll
        for (int q = 0; q < 4; ++q) ad[q] = av[q];
        h16x8* bd = reinterpret_cast<h16x8*>(&Bs[tid * LDA]);
        #pragma unroll
        for (int q = 0; q < 8; ++q) bd[q] = bv[q];
        __syncthreads();

        if (c < 1) LDC2(c + 1);

        #pragma unroll
        for (int kk = 0; kk < 64; kk += 32) {
            h16x8 a0 = *reinterpret_cast<const h16x8*>(&As[(wave*32      + l15) * LDA + kk + quad*8]);
            h16x8 a1 = *reinterpret_cast<const h16x8*>(&As[(wave*32 + 16 + l15) * LDA + kk + quad*8]);
            #pragma unroll
            for (int nt = 0; nt < 16; ++nt) {
                h16x8 b = *reinterpret_cast<const h16x8*>(&Bs[(nt*16 + l15) * LDA + kk + quad*8]);
                acc[0][nt] = __builtin_amdgcn_mfma_f32_16x16x32_f16(a0, b, acc[0][nt], 0, 0, 0);
                acc[1][nt] = __builtin_amdgcn_mfma_f32_16x16x32_f16(a1, b, acc[1][nt], 0, 0, 0);
            }
        }
    }
#undef LDC2

    // ---- epilogue: +b2, LN(256), gate, LN(128), store fp16 ----
    float bias[16], gg[16], bb[16];
    #pragma unroll
    for (int nt = 0; nt < 16; ++nt) {
        const int cc = nt * 16 + l15;
        bias[nt] = b2[cc]; gg[nt] = g2[cc]; bb[nt] = be2[cc];
    }
    float g2c[8], b2c[8];
    #pragma unroll
    for (int nt = 0; nt < 8; ++nt) {
        const int cc = nt * 16 + l15;
        g2c[nt] = g22[cc]; b2c[nt] = be22[cc];
    }
    #pragma unroll
    for (int mt = 0; mt < 2; ++mt) {
        #pragma unroll
        for (int rg = 0; rg < 4; ++rg) {
            float v[16];
            float s = 0.f, s2 = 0.f;
            #pragma unroll
            for (int nt = 0; nt < 16; ++nt) {
                v[nt] = acc[mt][nt][rg] + bias[nt];
                s += v[nt]; s2 += v[nt] * v[nt];
            }
            #pragma unroll
            for (int m = 1; m < 16; m <<= 1) {
                s  += __shfl_xor(s,  m, 64);
                s2 += __shfl_xor(s2, m, 64);
            }
            const float mean = s * (1.f / 256.f);
            const float var  = s2 * (1.f / 256.f) - mean * mean;
            const float inv  = rsqrtf(var + EPS);
            float msg[8];
            float t = 0.f, t2 = 0.f;
            #pragma unroll
            for (int nt = 0; nt < 8; ++nt) {
                const float f  = (v[nt]     - mean) * inv * gg[nt]     + bb[nt];
                const float co = (v[nt + 8] - mean) * inv * gg[nt + 8] + bb[nt + 8];
                const float m_ = (1.f / (1.f + __expf(-f))) * tanhf(co);
                msg[nt] = m_; t += m_; t2 += m_ * m_;
            }
            #pragma unroll
            for (int m = 1; m < 16; m <<= 1) {
                t  += __shfl_xor(t,  m, 64);
                t2 += __shfl_xor(t2, m, 64);
            }
            const float mean2 = t * (1.f / 128.f);
            const float var2  = t2 * (1.f / 128.f) - mean2 * mean2;
            const float inv2  = rsqrtf(var2 + EPS);
            const size_t rowg = (size_t)(m0 + wave * 32 + mt * 16 + quad * 4 + rg);
            #pragma unroll
            for (int nt = 0; nt < 8; ++nt) {
                const float o = (msg[nt] - mean2) * inv2 * g2c[nt] + b2c[nt];
                c2emb[rowg * D + nt * 16 + l15] = (h16)o;
            }
        }
    }
}

// ---------------------------------------------------------------------------
// final: c3_emb = LN(128)(acc3); out = tanh(edge + c2_emb + c3_emb).
// acc3 lives in d_out (fp32) and is overwritten in place. One wave per edge.
// ---------------------------------------------------------------------------
__global__ __launch_bounds__(256) void final_kernel(
    const float* __restrict__ edge, const h16* __restrict__ c2emb,
    const float* __restrict__ g32, const float* __restrict__ be32,
    float* out)
{
    const int lane = threadIdx.x & 63;
    const int wave = threadIdx.x >> 6;
    const size_t e = (size_t)blockIdx.x * 4 + wave;
    const int c0 = lane * 2;

    const float2 v = *reinterpret_cast<const float2*>(&out[e * D + c0]);  // acc3
    float s  = v.x + v.y;
    float s2 = v.x * v.x + v.y * v.y;
    #pragma unroll
    for (int m = 1; m < 64; m <<= 1) {
        s  += __shfl_xor(s,  m, 64);
        s2 += __shfl_xor(s2, m, 64);
    }
    const float mean = s * (1.f / 128.f);
    const float var  = s2 * (1.f / 128.f) - mean * mean;
    const float inv  = rsqrtf(var + EPS);
    const float c3a = (v.x - mean) * inv * g32[c0]     + be32[c0];
    const float c3b = (v.y - mean) * inv * g32[c0 + 1] + be32[c0 + 1];

    const float2 ev = *reinterpret_cast<const float2*>(&edge[e * D + c0]);
    const float ca = (float)c2emb[e * D + c0];
    const float cb = (float)c2emb[e * D + c0 + 1];
    float2 o;
    o.x = tanhf(ev.x + ca + c3a);
    o.y = tanhf(ev.y + cb + c3b);
    *reinterpret_cast<float2*>(&out[e * D + c0]) = o;
}

// ---------------------------------------------------------------------------
extern "C" void kernel_launch(void* const* d_in, const int* in_sizes, int n_in,
                              void* d_out, int out_size, void* d_ws, size_t ws_size,
                              hipStream_t stream)
{
    const float* node   = (const float*)d_in[0];
    const float* edge   = (const float*)d_in[1];
    const int*   e_i    = (const int*)d_in[2];
    const int*   e_j    = (const int*)d_in[3];
    const int*   idx_i  = (const int*)d_in[4];
    const int*   idx_j  = (const int*)d_in[5];
    const int*   idx_k  = (const int*)d_in[6];
    const int*   idx_ji = (const int*)d_in[7];
    const int*   idx_kj = (const int*)d_in[8];
    const float* W2     = (const float*)d_in[9];
    const float* b2     = (const float*)d_in[10];
    const float* W3     = (const float*)d_in[11];
    const float* b3     = (const float*)d_in[12];
    const float* g_c2   = (const float*)d_in[13];
    const float* be_c2  = (const float*)d_in[14];
    const float* g_c3   = (const float*)d_in[15];
    const float* be_c3  = (const float*)d_in[16];
    const float* g_c22  = (const float*)d_in[17];
    const float* be_c22 = (const float*)d_in[18];
    const float* g_c32  = (const float*)d_in[19];
    const float* be_c32 = (const float*)d_in[20];

    // ws layout (fp16): W3h [256*640] | W2h [256*128] | nodeh [N*128] |
    //                   c2emb [E*128] | edgeh [E*128] (optional)
    h16* W3h   = (h16*)d_ws;
    h16* W2h   = W3h + 256 * K3;
    h16* nodeh = W2h + 256 * D;
    h16* c2emb = nodeh + (size_t)NN * D;
    h16* edgeh = c2emb + (size_t)EE * D;
    const size_t need = ((size_t)256 * K3 + 256 * D + (size_t)NN * D
                         + 2 * (size_t)EE * D) * sizeof(h16);
    const bool use_edgeh = ws_size >= need;

    float* acc3 = (float*)d_out;   // fp32 scatter accumulator, finalized in place
    float* out  = (float*)d_out;

    hipMemsetAsync(d_out, 0, (size_t)EE * D * sizeof(float), stream);
    cvt_f32_f16<<<dim3((256 * K3 / 8 + 255) / 256), dim3(256), 0, stream>>>(W3, W3h, 256 * K3 / 8);
    cvt_f32_f16<<<dim3((256 * D  / 8 + 255) / 256), dim3(256), 0, stream>>>(W2, W2h, 256 * D / 8);
    cvt_f32_f16<<<dim3((NN * D   / 8 + 255) / 256), dim3(256), 0, stream>>>(node, nodeh, NN * D / 8);
    if (use_edgeh)
        cvt_f32_f16<<<dim3((EE * D / 8 + 255) / 256), dim3(256), 0, stream>>>(edge, edgeh, EE * D / 8);

    c3_kernel<<<dim3(TT / 128), dim3(256), 0, stream>>>(
        nodeh, edge, use_edgeh ? edgeh : (const h16*)nullptr,
        idx_i, idx_j, idx_k, idx_ji, idx_kj, W3h, b3, g_c3, be_c3, acc3);
    c2_kernel<<<dim3(EE / 128), dim3(256), 0, stream>>>(
        nodeh, e_i, e_j, W2h, b2, g_c2, be_c2, g_c22, be_c22, c2emb);
    final_kernel<<<dim3(EE / 4), dim3(256), 0, stream>>>(
        edge, c2emb, g_c32, be_c32, out);
}